// Round 9
// baseline (474.052 us; speedup 1.0000x reference)
//
#include <hip/hip_runtime.h>
#include <math.h>

// Shapes: B=32, S=512, I=64, H=512, E=8, P=96, O=64, EM=512; D = S*I = 32768.
#define DIMK 32768

__device__ __forceinline__ void fma4(float4& a, float s, const float4 w) {
  a.x += s * w.x; a.y += s * w.y; a.z += s * w.z; a.w += s * w.w;
}

// block sum over 512 threads via shuffles
__device__ __forceinline__ float bsum8(float v, volatile float* r8) {
  for (int o = 1; o < 64; o <<= 1) v += __shfl_xor(v, o);
  const int w = threadIdx.x >> 6;
  __syncthreads();
  if ((threadIdx.x & 63) == 0) r8[w] = v;
  __syncthreads();
  float s = 0.f;
#pragma unroll
  for (int i = 0; i < 8; ++i) s += r8[i];
  return s;
}

// ---------------------------------------------------------------------------
// K1: bid<512: gemm1 k-split tile, 512 threads (16 waves/CU at 2 blocks/CU);
//     bid>=512 (8 blocks): he_all[e][b][h] = relu(x_last @ eW1[e] + eb1[e]).
__global__ __launch_bounds__(512, 4) void k1_gemm1_he(const float* __restrict__ x,
                                                      const float* __restrict__ gW1,
                                                      const float* __restrict__ eW1,
                                                      const float* __restrict__ eb1,
                                                      float* __restrict__ part,
                                                      float* __restrict__ he_all) {
  __shared__ __align__(16) float S[16512];  // As 32x260 + Ws 64x128 = 66 KB
  const int t = threadIdx.x;
  if (blockIdx.x < 512) {
    const int mt = blockIdx.x & 3, ks = blockIdx.x >> 2;
    const int m0 = mt * 128, k0 = ks * 256;
    float* As = S;          // 32 x 260
    float* Ws = S + 8320;   // 64 x 128
    for (int i = t; i < 2048; i += 512) {
      int b = i >> 6, q = i & 63;
      *(float4*)&As[b * 260 + q * 4] = *(const float4*)(x + (size_t)b * DIMK + k0 + q * 4);
    }
    const float* Wp = gW1 + (size_t)k0 * 512 + m0;
    float4 wreg[4];
#pragma unroll
    for (int j = 0; j < 4; ++j) {
      int i = t + j * 512, r = i >> 5, q = i & 31;
      wreg[j] = *(const float4*)(Wp + (size_t)r * 512 + q * 4);
    }
    const int mf = t & 31, rg = t >> 5;  // rg 0..15 -> 2 rows each
    const int r0 = rg * 2;
    float4 acc0 = make_float4(0.f, 0.f, 0.f, 0.f), acc1 = acc0;
    for (int s = 0; s < 4; ++s) {
      __syncthreads();
#pragma unroll
      for (int j = 0; j < 4; ++j) {
        int i = t + j * 512, r = i >> 5, q = i & 31;
        *(float4*)&Ws[r * 128 + q * 4] = wreg[j];
      }
      __syncthreads();
      if (s < 3) {
        const float* Wn = Wp + (size_t)(s + 1) * 64 * 512;
#pragma unroll
        for (int j = 0; j < 4; ++j) {
          int i = t + j * 512, r = i >> 5, q = i & 31;
          wreg[j] = *(const float4*)(Wn + (size_t)r * 512 + q * 4);
        }
      }
      const float* ab0 = As + r0 * 260 + s * 64;
      const float* ab1 = ab0 + 260;
#pragma unroll 8
      for (int k = 0; k < 64; ++k) {
        float4 wv = *(const float4*)&Ws[k * 128 + mf * 4];
        fma4(acc0, ab0[k], wv);
        fma4(acc1, ab1[k], wv);
      }
    }
    float* op = part + ((size_t)ks * 32 + r0) * 512 + m0 + mf * 4;
    *(float4*)op = acc0;
    *(float4*)(op + 512) = acc1;
  } else {
    const int e = blockIdx.x - 512;   // 0..7, h = t
    float* xs = S;                    // 32 x 64
    {
      int b = t >> 4, q = t & 15;
      *(float4*)&xs[b * 64 + q * 4] = *(const float4*)(x + (size_t)b * DIMK + 32704 + q * 4);
    }
    __syncthreads();
    float acc[32];
#pragma unroll
    for (int b = 0; b < 32; ++b) acc[b] = 0.f;
    const float* w1 = eW1 + (size_t)e * 32768 + t;
#pragma unroll 8
    for (int k = 0; k < 64; ++k) {
      float wk = w1[(size_t)k * 512];
#pragma unroll
      for (int b = 0; b < 32; ++b) acc[b] += xs[b * 64 + k] * wk;
    }
    float bb = eb1[e * 512 + t];
    for (int b = 0; b < 32; ++b)
      he_all[((size_t)e * 32 + b) * 512 + t] = fmaxf(acc[b] + bb, 0.f);
  }
}

// ---------------------------------------------------------------------------
// K2: bid<64: y1 = gb1 + sum_ks part (kred). bid>=64: eW2 GEMM full-K -> eo.
__global__ __launch_bounds__(256) void k2_red_eg(const float* __restrict__ part,
                                                 const float* __restrict__ gb1,
                                                 const float* __restrict__ he_all,
                                                 const float* __restrict__ eW2,
                                                 float* __restrict__ y1,
                                                 float* __restrict__ eo) {
  __shared__ __align__(16) float S[16512];
  const int t = threadIdx.x;
  if (blockIdx.x < 64) {
    const int b = blockIdx.x >> 1, half = blockIdx.x & 1;
    const int m = half * 256 + t;
    const float* p = part + (size_t)b * 512 + m;
    float a0 = 0.f, a1 = 0.f, a2 = 0.f, a3 = 0.f;
#pragma unroll 8
    for (int ks = 0; ks < 128; ks += 4) {
      a0 += p[(size_t)(ks + 0) * 16384];
      a1 += p[(size_t)(ks + 1) * 16384];
      a2 += p[(size_t)(ks + 2) * 16384];
      a3 += p[(size_t)(ks + 3) * 16384];
    }
    y1[b * 512 + m] = gb1[m] + a0 + a1 + a2 + a3;
  } else {
    const int v = blockIdx.x - 64;
    const int e = v >> 3, mt = v & 7;
    const int m0 = mt * 64;
    float* As = S;          // 32 x 260 (one 256-k half)
    float* Ws = S + 8320;   // 128 x 64
    const int mf = t & 15, b0 = (t >> 4) * 2;
    float4 acc0 = make_float4(0.f, 0.f, 0.f, 0.f), acc1 = acc0;
    const float* Ae = he_all + (size_t)e * 16384;
    const float* We = eW2 + (size_t)e * 262144 + m0;
    for (int kh = 0; kh < 2; ++kh) {
      __syncthreads();
      for (int i = t; i < 2048; i += 256) {
        int bb = i >> 6, q = i & 63;
        *(float4*)&As[bb * 260 + q * 4] =
            *(const float4*)(Ae + (size_t)bb * 512 + kh * 256 + q * 4);
      }
      for (int sub = 0; sub < 2; ++sub) {
        __syncthreads();
        const float* wp = We + (size_t)(kh * 256 + sub * 128) * 512;
        for (int i = t; i < 2048; i += 256) {
          int r = i >> 4, q = i & 15;
          *(float4*)&Ws[r * 64 + q * 4] = *(const float4*)(wp + (size_t)r * 512 + q * 4);
        }
        __syncthreads();
        const float* ar0 = As + b0 * 260 + sub * 128;
        const float* ar1 = ar0 + 260;
#pragma unroll 8
        for (int k = 0; k < 128; ++k) {
          float4 wv = *(const float4*)&Ws[k * 64 + mf * 4];
          fma4(acc0, ar0[k], wv);
          fma4(acc1, ar1[k], wv);
        }
      }
    }
    float* op = eo + ((size_t)e * 32 + b0) * 512 + m0 + mf * 4;
    *(float4*)op = acc0;
    *(float4*)(op + 512) = acc1;
  }
}

// ---------------------------------------------------------------------------
// lngemm: out = [LN(in)·g+b (opt relu)] @ W + bias. K=512 fixed, M param.
// grid M/32 blocks, block 256. A (32x512) loaded fully per block; per-row LN
// in-block; W m-slice streamed in 4 sub-stages (weights read once grid-wide).
__global__ __launch_bounds__(256) void k_lngemm(const float* __restrict__ in,
                                                const float* __restrict__ lnG,
                                                const float* __restrict__ lnB,
                                                int doLN, int doRelu,
                                                const float* __restrict__ W,
                                                const float* __restrict__ bias,
                                                int M, float* __restrict__ outp) {
  __shared__ __align__(16) float As[32 * 520];  // 66.6 KB
  __shared__ __align__(16) float Ws[128 * 32];  // 16 KB
  const int t = threadIdx.x;
  const int m0 = blockIdx.x * 32;
  for (int i = t; i < 4096; i += 256) {
    int b = i >> 7, q = i & 127;
    *(float4*)&As[b * 520 + q * 4] = *(const float4*)(in + (size_t)b * 512 + q * 4);
  }
  __syncthreads();
  if (doLN) {
    const int w = t >> 6, l = t & 63;
    for (int j = 0; j < 8; ++j) {
      const int r = w * 8 + j;
      float v[8], s = 0.f;
#pragma unroll
      for (int jj = 0; jj < 8; ++jj) { v[jj] = As[r * 520 + l + jj * 64]; s += v[jj]; }
      for (int o = 1; o < 64; o <<= 1) s += __shfl_xor(s, o);
      float mean = s * (1.f / 512.f);
      float q = 0.f;
#pragma unroll
      for (int jj = 0; jj < 8; ++jj) { float d = v[jj] - mean; q += d * d; }
      for (int o = 1; o < 64; o <<= 1) q += __shfl_xor(q, o);
      float rr = rsqrtf(q * (1.f / 512.f) + 1e-5f);
#pragma unroll
      for (int jj = 0; jj < 8; ++jj) {
        int c = l + jj * 64;
        float nv = (v[jj] - mean) * rr * lnG[c] + lnB[c];
        As[r * 520 + c] = doRelu ? fmaxf(nv, 0.f) : nv;
      }
    }
  }
  const int mf = t & 7, b = t >> 3;
  float4 acc = make_float4(0.f, 0.f, 0.f, 0.f);
  for (int sub = 0; sub < 4; ++sub) {
    __syncthreads();
    for (int i = t; i < 1024; i += 256) {
      int r = i >> 3, q = i & 7;
      *(float4*)&Ws[r * 32 + q * 4] = *(const float4*)(W + (size_t)(sub * 128 + r) * M + m0 + q * 4);
    }
    __syncthreads();
    const float* ar = As + b * 520 + sub * 128;
#pragma unroll 8
    for (int k = 0; k < 128; ++k)
      fma4(acc, ar[k], *(const float4*)&Ws[k * 32 + mf * 4]);
  }
  float4 bb = *(const float4*)(bias + m0 + mf * 4);
  acc.x += bb.x; acc.y += bb.y; acc.z += bb.z; acc.w += bb.w;
  *(float4*)(outp + (size_t)b * M + m0 + mf * 4) = acc;
}

// ---------------------------------------------------------------------------
// k_gate_ffuse: per b: h2 = relu(LN(y2)); emb = h2@gW3+gb3; gate softmax;
// fused[b] = sum_e w[e]*(eo[e][b]+eb2[e]). 32 blocks x 512.
__global__ __launch_bounds__(512) void k_gate_ffuse(const float* __restrict__ y2,
                                                    const float* __restrict__ g2g, const float* __restrict__ g2b,
                                                    const float* __restrict__ gW3, const float* __restrict__ gb3,
                                                    const float* __restrict__ protos, const float* __restrict__ temp,
                                                    const float* __restrict__ eo, const float* __restrict__ eb2,
                                                    float* __restrict__ fused) {
  __shared__ float h2b[512], embp[512], embs[128], d2s[8], wl[8];
  __shared__ float r8[8];
  const int b = blockIdx.x, t = threadIdx.x;
  float a = y2[b * 512 + t];
  float mean = bsum8(a, r8) * (1.f / 512.f);
  float d = a - mean;
  float var = bsum8(d * d, r8) * (1.f / 512.f);
  h2b[t] = fmaxf(d * rsqrtf(var + 1e-5f) * g2g[t] + g2b[t], 0.f);
  __syncthreads();
  {
    const int kh = t >> 7, m = t & 127;
    float c = 0.f;
    const float* w3 = gW3 + m;
#pragma unroll 8
    for (int k = kh * 128; k < kh * 128 + 128; ++k) c += h2b[k] * w3[(size_t)k * 128];
    embp[t] = c;
  }
  __syncthreads();
  if (t < 128) embs[t] = gb3[t] + embp[t] + embp[128 + t] + embp[256 + t] + embp[384 + t];
  __syncthreads();
  {
    const int e = t >> 6, l = t & 63;
    float z0 = embs[l] - protos[e * 128 + l];
    float z1 = embs[l + 64] - protos[e * 128 + 64 + l];
    float q = z0 * z0 + z1 * z1;
    for (int o = 1; o < 64; o <<= 1) q += __shfl_xor(q, o);
    if (l == 0) d2s[e] = q;
  }
  __syncthreads();
  if (t == 0) {
    float tt = fminf(fmaxf(temp[0], 0.1f), 5.0f);
    float lg[8], mx = -1e30f;
#pragma unroll
    for (int e = 0; e < 8; ++e) {
      float dist = sqrtf(fmaxf(d2s[e], 1e-12f));
      lg[e] = -dist / tt;
      mx = fmaxf(mx, lg[e]);
    }
    float se = 0.f;
#pragma unroll
    for (int e = 0; e < 8; ++e) { lg[e] = expf(lg[e] - mx); se += lg[e]; }
#pragma unroll
    for (int e = 0; e < 8; ++e) wl[e] = lg[e] / se;
  }
  __syncthreads();
  float acc = 0.f;
#pragma unroll
  for (int e = 0; e < 8; ++e)
    acc += wl[e] * (eo[((size_t)e * 32 + b) * 512 + t] + eb2[e * 512 + t]);
  fused[b * 512 + t] = acc;
}

// ---------------------------------------------------------------------------
// k_final: pp = relu(LN256(y5)) in-block; out = LN64(pp @ pW2[:,pi] + pb2).
// grid (96 pi, 4 bq), block 256.
__global__ __launch_bounds__(256) void k_final(const float* __restrict__ y5,
                                               const float* __restrict__ plg, const float* __restrict__ plb,
                                               const float* __restrict__ pW2, const float* __restrict__ pb2,
                                               const float* __restrict__ ong, const float* __restrict__ onb,
                                               float* __restrict__ outp) {
  __shared__ __align__(16) float Ws[256 * 64];  // 64 KB
  __shared__ __align__(16) float As[8 * 260];
  const int pi = blockIdx.x, bq = blockIdx.y;
  const int t = threadIdx.x;
  const float* wp = pW2 + pi * 64;
  for (int i = t; i < 4096; i += 256) {
    int r = i >> 4, q = i & 15;
    *(float4*)&Ws[r * 64 + q * 4] = *(const float4*)(wp + (size_t)r * 6144 + q * 4);
  }
  {
    const int row = t >> 5, l32 = t & 31;
    const int b = bq * 8 + row;
    float v[8], s = 0.f;
#pragma unroll
    for (int j = 0; j < 8; ++j) { v[j] = y5[(size_t)b * 256 + l32 + j * 32]; s += v[j]; }
    s += __shfl_xor(s, 1); s += __shfl_xor(s, 2); s += __shfl_xor(s, 4);
    s += __shfl_xor(s, 8); s += __shfl_xor(s, 16);
    float mean = s * (1.f / 256.f);
    float q = 0.f;
#pragma unroll
    for (int j = 0; j < 8; ++j) { float d = v[j] - mean; q += d * d; }
    q += __shfl_xor(q, 1); q += __shfl_xor(q, 2); q += __shfl_xor(q, 4);
    q += __shfl_xor(q, 8); q += __shfl_xor(q, 16);
    float rr = rsqrtf(q * (1.f / 256.f) + 1e-5f);
#pragma unroll
    for (int j = 0; j < 8; ++j) {
      int c = l32 + j * 32;
      As[row * 260 + c] = fmaxf((v[j] - mean) * rr * plg[c] + plb[c], 0.f);
    }
  }
  __syncthreads();
  const int w = t >> 6, o = t & 63;
  const int bl = w * 2;
  float a0 = 0.f, a1 = 0.f;
  const float* ar0 = As + bl * 260;
  const float* ar1 = ar0 + 260;
#pragma unroll 8
  for (int k = 0; k < 256; ++k) {
    float wv = Ws[k * 64 + o];
    a0 += ar0[k] * wv;
    a1 += ar1[k] * wv;
  }
  float bias = pb2[pi * 64 + o];
  float gv = ong[o], bv = onb[o];
  float accs[2] = {a0 + bias, a1 + bias};
#pragma unroll
  for (int rr = 0; rr < 2; ++rr) {
    float a = accs[rr];
    float s = a;
    for (int off = 1; off < 64; off <<= 1) s += __shfl_xor(s, off);
    float mean = s * (1.f / 64.f);
    float d = a - mean;
    float q = d * d;
    for (int off = 1; off < 64; off <<= 1) q += __shfl_xor(q, off);
    float r = rsqrtf(q * (1.f / 64.f) + 1e-5f);
    int b = bq * 8 + bl + rr;
    outp[((size_t)b * 96 + pi) * 64 + o] = d * r * gv + bv;
  }
}

extern "C" void kernel_launch(void* const* d_in, const int* in_sizes, int n_in,
                              void* d_out, int out_size, void* d_ws, size_t ws_size,
                              hipStream_t stream) {
  (void)in_sizes; (void)n_in; (void)out_size; (void)ws_size;
  const float* x      = (const float*)d_in[0];
  const float* gW1    = (const float*)d_in[1];
  const float* gb1    = (const float*)d_in[2];
  const float* gln1_g = (const float*)d_in[3];
  const float* gln1_b = (const float*)d_in[4];
  const float* gW2    = (const float*)d_in[5];
  const float* gb2    = (const float*)d_in[6];
  const float* gln2_g = (const float*)d_in[7];
  const float* gln2_b = (const float*)d_in[8];
  const float* gW3    = (const float*)d_in[9];
  const float* gb3    = (const float*)d_in[10];
  const float* protos = (const float*)d_in[11];
  const float* temp   = (const float*)d_in[12];
  const float* eW1    = (const float*)d_in[13];
  const float* eb1    = (const float*)d_in[14];
  const float* eW2    = (const float*)d_in[15];
  const float* eb2    = (const float*)d_in[16];
  const float* fW1    = (const float*)d_in[17];
  const float* fb1    = (const float*)d_in[18];
  const float* fln_g  = (const float*)d_in[19];
  const float* fln_b  = (const float*)d_in[20];
  const float* fW2    = (const float*)d_in[21];
  const float* fb2    = (const float*)d_in[22];
  const float* ln_g   = (const float*)d_in[23];
  const float* ln_b   = (const float*)d_in[24];
  const float* pW1    = (const float*)d_in[25];
  const float* pb1    = (const float*)d_in[26];
  const float* pln_g  = (const float*)d_in[27];
  const float* pln_b  = (const float*)d_in[28];
  const float* pW2    = (const float*)d_in[29];
  const float* pb2    = (const float*)d_in[30];
  const float* on_g   = (const float*)d_in[31];
  const float* on_b   = (const float*)d_in[32];
  float* out = (float*)d_out;

  float* ws     = (float*)d_ws;
  float* part   = ws;               // 2,097,152
  float* he_all = ws + 2097152;     // 131,072
  float* eo     = ws + 2228224;     // 131,072
  float* y1     = ws + 2359296;     // 16,384
  float* y2     = ws + 2375680;     // 16,384
  float* fused  = ws + 2392064;     // 16,384
  float* y3     = ws + 2408448;     // 16,384
  float* y4     = ws + 2424832;     // 16,384
  float* y5     = ws + 2441216;     // 8,192 (end 2,449,408 fl = 9.8 MB)

  k1_gemm1_he<<<520, 512, 0, stream>>>(x, gW1, eW1, eb1, part, he_all);
  k2_red_eg<<<128, 256, 0, stream>>>(part, gb1, he_all, eW2, y1, eo);
  k_lngemm<<<16, 256, 0, stream>>>(y1, gln1_g, gln1_b, 1, 1, gW2, gb2, 512, y2);
  k_gate_ffuse<<<32, 512, 0, stream>>>(y2, gln2_g, gln2_b, gW3, gb3, protos, temp,
                                       eo, eb2, fused);
  k_lngemm<<<16, 256, 0, stream>>>(fused, gb3 /*unused*/, gb3 /*unused*/, 0, 0,
                                   fW1, fb1, 512, y3);
  k_lngemm<<<16, 256, 0, stream>>>(y3, fln_g, fln_b, 1, 1, fW2, fb2, 512, y4);
  k_lngemm<<<8, 256, 0, stream>>>(y4, ln_g, ln_b, 1, 0, pW1, pb1, 256, y5);
  k_final<<<dim3(96, 4), 256, 0, stream>>>(y5, pln_g, pln_b, pW2, pb2, on_g, on_b, out);
}